// Round 15
// baseline (1963.856 us; speedup 1.0000x reference)
//
#include <hip/hip_runtime.h>
#include <hip/hip_bf16.h>

typedef __attribute__((ext_vector_type(8))) short bfrag8;   // 8 bf16 in 4 VGPRs
typedef __attribute__((ext_vector_type(4))) float f32x4;

#define DIV_UP(a,b) (((a)+(b)-1)/(b))

__device__ __forceinline__ float sigm(float x){ return 1.0f/(1.0f + __expf(-x)); }
__device__ __forceinline__ float fast_tanh(float x){
  float ax = fabsf(x);
  float t = __expf(-2.0f*ax);
  float r = (1.0f - t)/(1.0f + t);
  return copysignf(r, x);
}
__device__ __forceinline__ float bf2f(short s){
  unsigned int u = ((unsigned int)(unsigned short)s) << 16;
  return __uint_as_float(u);
}
__device__ __forceinline__ unsigned short f2bf_bits(float x){
  __hip_bfloat16 b = __float2bfloat16(x);
  return *reinterpret_cast<unsigned short*>(&b);
}

#define GLOAD_LDS16(g, l) \
  __builtin_amdgcn_global_load_lds((const __attribute__((address_space(1))) void*)(g), \
                                   (__attribute__((address_space(3))) void*)(l), 16, 0, 0)

// ---------------- merged weight / embedding conversion (1 launch) ----------------
__global__ void conv_all(const float* __restrict__ emb, const float* __restrict__ Wf,
                         const float* __restrict__ Ui, const float* __restrict__ Uf,
                         __hip_bfloat16* __restrict__ oemb, __hip_bfloat16* __restrict__ owiou,
                         __hip_bfloat16* __restrict__ oucat){
  int idx = blockIdx.x*256 + threadIdx.x;
  if (idx < 32000*80) {
    int v = idx / 80, c = idx - v*80;
    ushort4 r;
    if (c < 75) {
      float4 f = *(const float4*)(emb + (size_t)v*300 + c*4);
      r.x = f2bf_bits(f.x); r.y = f2bf_bits(f.y); r.z = f2bf_bits(f.z); r.w = f2bf_bits(f.w);
    } else { r.x = r.y = r.z = r.w = 0; }
    *(ushort4*)((unsigned short*)oemb + (size_t)v*320 + c*4) = r;
    return;
  }
  idx -= 32000*80;
  if (idx < 768*320) {
    int n = idx / 320, k = idx - n*320;
    int eg = n / 48, rem = n - eg*48, gate = rem >> 4, es = rem & 15;
    int e = eg*16 + es;
    owiou[(size_t)n*320 + k] = __float2bfloat16(k < 300 ? Wf[(size_t)k*768 + gate*256 + e] : 0.0f);
    return;
  }
  idx -= 768*320;
  if (idx < 1280*512) {
    int n = idx >> 9, k = idx & 511;
    int eg = n / 80, rem = n - eg*80, gate = rem >> 4, es = rem & 15;
    int e = eg*16 + es;
    float v = (gate < 3) ? Ui[(size_t)k*768 + gate*256 + e]
                         : Uf[(size_t)k*512 + (gate-3)*256 + e];
    oucat[(size_t)n*512 + k] = __float2bfloat16(v);
  }
}

// ---------------- fused GEMM + gates, 2-phase double-buffered pipeline (round-8/10/12 best) ----
// Verified local optimum; bracketing ledger in repo history (r4,r5,r9,r11,r13).
// UNTOUCHED from round 12/14 to preserve codegen of the hot lvl-1/2/3 dispatches.
template<int NG, bool G2>
__global__ __launch_bounds__(256, 3) void gemm_fused(
    const char* __restrict__ Ab,      // A bytes (direct) | h_voc bytes (G2: gather pairs)
    const int*  __restrict__ wid,     // G2 only: leaf wordids (children 2m, 2m+1)
    const char* __restrict__ Btb,     // interleaved [N][K] bf16
    int M, int K, int Kb,             // Kb = A row stride bytes (direct mode)
    const float* __restrict__ b_iou,  // [768] original layout
    const float* __restrict__ b_f,    // [512] (NG=5)
    const float* __restrict__ cprev,  // fp32 children c (table when G2)
    __hip_bfloat16* __restrict__ Hout, float* __restrict__ Cout)
{
  constexpr int GW  = NG*16;          // wave col width (one e-group, NG gates)
  constexpr int BN  = 2*GW;           // block cols
  constexpr int BCH = BN*4;           // B chunks (16B) per K-step
  constexpr int BUF = 8192 + BN*64;   // bytes per (A,B) buffer pair
  __shared__ __align__(16) char lds[2*BUF];

  const int lx = blockIdx.y & 7;
  const int ly = ((blockIdx.y >> 3) << 3) | (blockIdx.x & 7);
  const int row0 = ly*128;
  if (row0 >= M) return;              // padded grid.y tail (uniform per block)

  const int t = threadIdx.x, lane = t & 63, w = t >> 6;
  const int wr = w >> 1, wc = w & 1;
  const int frow = lane & 15, g = lane >> 4;
  const size_t colbase = (size_t)lx * BN;
  const size_t Kbyt = (size_t)K*2;

  const char* abase0[2]; const char* abase1[2];
  #pragma unroll
  for (int i = 0; i < 2; ++i) {
    int c = t + i*256;
    int rp = c >> 3, lc = (c & 7) ^ (rp & 7);
    int r = rp*2 + (lc >> 2), q = lc & 3;
    int row = row0 + r; row = row < M ? row : M-1;
    if constexpr (G2) {
      abase0[i] = Ab + (size_t)wid[2*row]  *512 + q*16;
      abase1[i] = Ab + (size_t)wid[2*row+1]*512 + q*16 - 512;
    } else {
      abase0[i] = Ab + (size_t)row*Kb + q*16;
      abase1[i] = abase0[i];
    }
  }
  const char* bbase[3];
  const int nb = (t < 128) ? ((NG==5) ? 3 : 2) : ((NG==5) ? 2 : 1);
  #pragma unroll
  for (int i = 0; i < 3; ++i) {
    int cb = t + i*256;
    if (cb < BCH) {
      int rp = cb >> 3, lc = (cb & 7) ^ (rp & 7);
      int r = rp*2 + (lc >> 2), q = lc & 3;
      bbase[i] = Btb + (colbase + r)*Kbyt + q*16;
    } else bbase[i] = Btb;
  }

  auto STAGE = [&](int b, int ks){
    const int kb0 = ks*64;
    char* la = lds + b*BUF;
    char* lb = la + 8192;
    #pragma unroll
    for (int i = 0; i < 2; ++i) {
      const char* s = (G2 && kb0 >= 512) ? abase1[i] + kb0 : abase0[i] + kb0;
      GLOAD_LDS16(s, la + (t + i*256)*16);
    }
    #pragma unroll
    for (int i = 0; i < 3; ++i)
      if (i < nb) GLOAD_LDS16(bbase[i] + kb0, lb + (t + i*256)*16);
  };

  const int fr2 = frow >> 1;
  const int pc  = (((frow & 1)*4 + g) ^ (fr2 & 7));
  const int aoff = wr*4096 + fr2*128 + pc*16;
  const int boff = wc*(GW*64) + fr2*128 + pc*16;

  f32x4 acc[4][NG] = {};
  const int nsteps = K >> 5;

  STAGE(0, 0);
  for (int ks = 0; ks < nsteps; ++ks) {
    const int b = ks & 1;
    if (ks + 1 < nsteps) {
      STAGE(b ^ 1, ks + 1);
      if constexpr (NG == 5) {
        if (w < 2) asm volatile("s_waitcnt vmcnt(5)" ::: "memory");
        else       asm volatile("s_waitcnt vmcnt(4)" ::: "memory");
      } else {
        if (w < 2) asm volatile("s_waitcnt vmcnt(4)" ::: "memory");
        else       asm volatile("s_waitcnt vmcnt(3)" ::: "memory");
      }
    } else {
      asm volatile("s_waitcnt vmcnt(0)" ::: "memory");
    }
    __builtin_amdgcn_s_barrier();
    asm volatile("" ::: "memory");

    const char* la = lds + b*BUF;
    const char* lb = la + 8192;
    bfrag8 af[4], bfv[NG];
    #pragma unroll
    for (int mi = 0; mi < 4; ++mi) af[mi] = *(const bfrag8*)(la + aoff + mi*1024);
    #pragma unroll
    for (int gi = 0; gi < NG; ++gi) bfv[gi] = *(const bfrag8*)(lb + boff + gi*1024);
    #pragma unroll
    for (int mi = 0; mi < 4; ++mi)
      #pragma unroll
      for (int gi = 0; gi < NG; ++gi)
        acc[mi][gi] = __builtin_amdgcn_mfma_f32_16x16x32_bf16(af[mi], bfv[gi], acc[mi][gi], 0, 0, 0);

    asm volatile("" ::: "memory");
    __builtin_amdgcn_s_barrier();
  }

  const int e = lx*32 + wc*16 + frow;
  const float bi = b_iou[e], bo = b_iou[256+e], bu = b_iou[512+e];
  float bf0 = 0.f, bf1 = 0.f;
  if constexpr (NG == 5) { bf0 = b_f[e]; bf1 = b_f[256+e]; }
  #pragma unroll
  for (int mi = 0; mi < 4; ++mi) {
    const int mb = row0 + wr*64 + mi*16 + g*4;
    #pragma unroll
    for (int r = 0; r < 4; ++r) {
      const int m = mb + r;
      if (m < M) {
        float cv = sigm(acc[mi][0][r] + bi) * fast_tanh(acc[mi][2][r] + bu);
        if constexpr (NG == 5) {
          const size_t c0i = G2 ? (size_t)wid[2*m]   : (size_t)(2*m);
          const size_t c1i = G2 ? (size_t)wid[2*m+1] : (size_t)(2*m+1);
          cv += sigm(acc[mi][3][r] + bf0) * cprev[c0i*256 + e]
              + sigm(acc[mi][4][r] + bf1) * cprev[c1i*256 + e];
        }
        Cout[(size_t)m*256 + e] = cv;
        Hout[(size_t)m*256 + e] = __float2bfloat16(sigm(acc[mi][1][r] + bo) * fast_tanh(cv));
      }
    }
  }
}

// ---------------- persistent tail: levels 4..11 in ONE launch, grid barriers between ----
// Grid = 8 x 64 = 512 blocks <= 768 capacity (256 CU x 3 blk; LDS 36.9 KB -> residency 2/CU)
// => all blocks co-resident, no deadlock. Barrier: monotonic counter, AGENT-scope acq_rel
// (emits cross-XCD L2 wb/inv), s_sleep spin; counter zeroed per launch via hipMemsetAsync
// (captured graph node -> deterministic across replays). Out-of-range blocks skip compute
// but hit every grid barrier; internal s_barriers stay block-uniform.
__device__ __forceinline__ void gridbar(unsigned* bar, unsigned target){
  __syncthreads();                       // all block stores drained (vmcnt 0 before s_barrier)
  if (threadIdx.x == 0) {
    __hip_atomic_fetch_add(bar, 1u, __ATOMIC_ACQ_REL, __HIP_MEMORY_SCOPE_AGENT);
    while (__hip_atomic_load(bar, __ATOMIC_ACQUIRE, __HIP_MEMORY_SCOPE_AGENT) < target)
      __builtin_amdgcn_s_sleep(2);
  }
  __syncthreads();
}

__global__ __launch_bounds__(256, 3) void gemm_tail(
    const char* __restrict__ hAllb,   // hAll as bytes (h rows of 512 B)
    const char* __restrict__ Btb,     // ucatT
    const float* __restrict__ b_iou, const float* __restrict__ b_f,
    float* __restrict__ cA, float* __restrict__ cB,
    __hip_bfloat16* __restrict__ hAll, unsigned* __restrict__ bar)
{
  constexpr int NG  = 5;
  constexpr int GW  = NG*16;
  constexpr int BN  = 2*GW;
  constexpr int BCH = BN*4;
  constexpr int BUF = 8192 + BN*64;
  constexpr int K   = 512, Kb = 1024;
  constexpr unsigned NB = 512;        // gridDim 8 x 64
  __shared__ __align__(16) char lds[2*BUF];

  const int lx = blockIdx.y & 7;
  const int ly = ((blockIdx.y >> 3) << 3) | (blockIdx.x & 7);
  const int t = threadIdx.x, lane = t & 63, w = t >> 6;
  const int wr = w >> 1, wc = w & 1;
  const int frow = lane & 15, g = lane >> 4;
  const size_t colbase = (size_t)lx * BN;
  const size_t Kbyt = (size_t)K*2;

  // B descriptors are level-invariant
  const char* bbase[3];
  const int nb = (t < 128) ? 3 : 2;
  #pragma unroll
  for (int i = 0; i < 3; ++i) {
    int cb = t + i*256;
    if (cb < BCH) {
      int rp = cb >> 3, lc = (cb & 7) ^ (rp & 7);
      int r = rp*2 + (lc >> 2), q = lc & 3;
      bbase[i] = Btb + (colbase + r)*Kbyt + q*16;
    } else bbase[i] = Btb;
  }
  const int fr2 = frow >> 1;
  const int pc  = (((frow & 1)*4 + g) ^ (fr2 & 7));
  const int aoff = wr*4096 + fr2*128 + pc*16;
  const int boff = wc*(GW*64) + fr2*128 + pc*16;
  const int e = lx*32 + wc*16 + frow;
  const float bi = b_iou[e], bo = b_iou[256+e], bu = b_iou[512+e];
  const float bf0 = b_f[e], bf1 = b_f[256+e];

  size_t inb = 98304, outb = 114688;  // row bases: lvl-3 out, lvl-4 out (hAll packing)
  unsigned bc = 0;
  for (int lvl = 4; lvl <= 11; ++lvl) {
    const int M = 65536 >> (lvl - 1);
    const float* cprev = ((lvl - 1) & 1) ? cA : cB;
    float*       cnew  = (lvl & 1) ? cA : cB;
    const int row0 = ly*128;
    if (row0 < M) {
      const char* Ab = hAllb + inb*512;
      __hip_bfloat16* Hout = hAll + outb*256;
      const char* abase[2];
      #pragma unroll
      for (int i = 0; i < 2; ++i) {
        int c = t + i*256;
        int rp = c >> 3, lc = (c & 7) ^ (rp & 7);
        int r = rp*2 + (lc >> 2), q = lc & 3;
        int row = row0 + r; row = row < M ? row : M-1;
        abase[i] = Ab + (size_t)row*Kb + q*16;
      }
      auto STAGE = [&](int b, int ks){
        const int kb0 = ks*64;
        char* la = lds + b*BUF;
        char* lb = la + 8192;
        #pragma unroll
        for (int i = 0; i < 2; ++i) GLOAD_LDS16(abase[i] + kb0, la + (t + i*256)*16);
        #pragma unroll
        for (int i = 0; i < 3; ++i)
          if (i < nb) GLOAD_LDS16(bbase[i] + kb0, lb + (t + i*256)*16);
      };

      f32x4 acc[4][NG] = {};
      const int nsteps = K >> 5;
      STAGE(0, 0);
      for (int ks = 0; ks < nsteps; ++ks) {
        const int b = ks & 1;
        if (ks + 1 < nsteps) {
          STAGE(b ^ 1, ks + 1);
          if (w < 2) asm volatile("s_waitcnt vmcnt(5)" ::: "memory");
          else       asm volatile("s_waitcnt vmcnt(4)" ::: "memory");
        } else {
          asm volatile("s_waitcnt vmcnt(0)" ::: "memory");
        }
        __builtin_amdgcn_s_barrier();
        asm volatile("" ::: "memory");

        const char* la = lds + b*BUF;
        const char* lb = la + 8192;
        bfrag8 af[4], bfv[NG];
        #pragma unroll
        for (int mi = 0; mi < 4; ++mi) af[mi] = *(const bfrag8*)(la + aoff + mi*1024);
        #pragma unroll
        for (int gi = 0; gi < NG; ++gi) bfv[gi] = *(const bfrag8*)(lb + boff + gi*1024);
        #pragma unroll
        for (int mi = 0; mi < 4; ++mi)
          #pragma unroll
          for (int gi = 0; gi < NG; ++gi)
            acc[mi][gi] = __builtin_amdgcn_mfma_f32_16x16x32_bf16(af[mi], bfv[gi], acc[mi][gi], 0, 0, 0);

        asm volatile("" ::: "memory");
        __builtin_amdgcn_s_barrier();
      }

      #pragma unroll
      for (int mi = 0; mi < 4; ++mi) {
        const int mb = row0 + wr*64 + mi*16 + g*4;
        #pragma unroll
        for (int r = 0; r < 4; ++r) {
          const int m = mb + r;
          if (m < M) {
            float cv = sigm(acc[mi][0][r] + bi) * fast_tanh(acc[mi][2][r] + bu)
                     + sigm(acc[mi][3][r] + bf0) * cprev[(size_t)(2*m)*256 + e]
                     + sigm(acc[mi][4][r] + bf1) * cprev[(size_t)(2*m+1)*256 + e];
            cnew[(size_t)m*256 + e] = cv;
            Hout[(size_t)m*256 + e] = __float2bfloat16(sigm(acc[mi][1][r] + bo) * fast_tanh(cv));
          }
        }
      }
    }
    if (lvl < 11) gridbar(bar, NB * (++bc));
    inb = outb; outb += M;
  }
}

// ---------------- vectorized output projection ----------------
__global__ void outproj_v(const __hip_bfloat16* __restrict__ h, int M,
                          const float* __restrict__ Wout, const float* __restrict__ bout,
                          float* __restrict__ out){
  const int t = threadIdx.x;
  const int half = t >> 5, l32 = t & 31;
  const int e0 = l32 * 8;
  float wv[8][5];
  #pragma unroll
  for (int j = 0; j < 8; ++j)
    #pragma unroll
    for (int cl = 0; cl < 5; ++cl) wv[j][cl] = Wout[(e0+j)*5 + cl];
  const float b0 = bout[0], b1 = bout[1], b2 = bout[2], b3 = bout[3], b4 = bout[4];
  for (int row = blockIdx.x*8 + half; row < M; row += gridDim.x*8) {
    bfrag8 hv = *(const bfrag8*)((const short*)h + (size_t)row*256 + e0);
    float a0=0,a1=0,a2=0,a3=0,a4=0;
    #pragma unroll
    for (int j = 0; j < 8; ++j) {
      float x = bf2f(hv[j]);
      a0 += x*wv[j][0]; a1 += x*wv[j][1]; a2 += x*wv[j][2]; a3 += x*wv[j][3]; a4 += x*wv[j][4];
    }
    #pragma unroll
    for (int off = 16; off; off >>= 1) {
      a0 += __shfl_down(a0, off); a1 += __shfl_down(a1, off);
      a2 += __shfl_down(a2, off); a3 += __shfl_down(a3, off); a4 += __shfl_down(a4, off);
    }
    if (l32 == 0) {
      float* op = out + (size_t)row*5;
      op[0]=a0+b0; op[1]=a1+b1; op[2]=a2+b2; op[3]=a3+b3; op[4]=a4+b4;
    }
  }
}

// ---------------- leaf output scatter: out[p] = outvoc[wordid[p]] ----------------
__global__ void leaf_scatter(const int* __restrict__ wid, const float* __restrict__ outvoc,
                             float* __restrict__ out){
  int p = blockIdx.x*256 + threadIdx.x;
  if (p >= 131072) return;
  const float* s = outvoc + (size_t)wid[p]*5;
  float* d = out + (size_t)p*5;
  #pragma unroll
  for (int j = 0; j < 5; ++j) d[j] = s[j];
}

extern "C" void kernel_launch(void* const* d_in, const int* in_sizes, int n_in,
                              void* d_out, int out_size, void* d_ws, size_t ws_size,
                              hipStream_t stream) {
  const int* wordid   = (const int*)d_in[0];
  const float* emb    = (const float*)d_in[1];
  const float* W_iou  = (const float*)d_in[2];
  const float* b_Wiou = (const float*)d_in[3];
  const float* U_iou  = (const float*)d_in[4];
  const float* b_Uiou = (const float*)d_in[5];
  const float* U_f    = (const float*)d_in[6];
  const float* b_Uf   = (const float*)d_in[7];
  const float* W_out  = (const float*)d_in[8];
  const float* b_out  = (const float*)d_in[9];
  float* out = (float*)d_out;

  char* p = (char*)d_ws;
  auto take = [&](size_t bytes){ char* r = p; p += (bytes + 255) & ~(size_t)255; return r; };
  __hip_bfloat16* wiouT  = (__hip_bfloat16*)take((size_t)768*320*2);
  __hip_bfloat16* ucatT  = (__hip_bfloat16*)take((size_t)1280*512*2);
  __hip_bfloat16* h_voc  = (__hip_bfloat16*)take((size_t)32000*256*2);   // 16.4 MB
  float*          c_voc  = (float*)take((size_t)32000*256*4);            // 32.8 MB
  float*          outvoc = (float*)take((size_t)32000*5*4);
  __hip_bfloat16* hAll   = (__hip_bfloat16*)take((size_t)131008*256*2);  // 67.1 MB (lvls 1-11 packed)
  float*          cA     = (float*)take((size_t)65536*256*4);            // 67.1 MB
  float*          cB     = (float*)take((size_t)32768*256*4);            // 33.6 MB
  unsigned*       bar    = (unsigned*)take(256);
  // embbf aliases cA: dead before first cA write (lvl-1 gates)
  __hip_bfloat16* embbf  = (__hip_bfloat16*)cA;                          // 20.5 MB

  auto ceil8 = [](int y){ return (y + 7) & ~7; };

  // ---- single merged conversion launch (emb + WiouT + UcatT) ----
  const int convN = 32000*80 + 768*320 + 1280*512;
  conv_all<<<DIV_UP(convN,256),256,0,stream>>>(emb, W_iou, U_iou, U_f, embbf, wiouT, ucatT);

  // ---- vocab precompute: h_voc/c_voc = leaf-gates(emb @ W_iou + b); outvoc = h_voc @ W_out + b ----
  gemm_fused<3,false><<<dim3(8,ceil8(250)),256,0,stream>>>(
      (const char*)embbf, nullptr, (const char*)wiouT, 32000, 320, 640,
      b_Wiou, nullptr, nullptr, h_voc, c_voc);
  outproj_v<<<1024,256,0,stream>>>(h_voc, 32000, W_out, b_out, outvoc);
  leaf_scatter<<<DIV_UP(131072,256),256,0,stream>>>(wordid, outvoc, out);

  // ---- level 1: gather children straight from vocab tables; h -> hAll[0:65536) ----
  gemm_fused<5,true><<<dim3(8,512),256,0,stream>>>(
      (const char*)h_voc, wordid, (const char*)ucatT, 65536, 512, 0,
      b_Uiou, b_Uf, c_voc, hAll, cA);

  // ---- levels 2..3 standalone (grids too large for guaranteed co-residency) ----
  const __hip_bfloat16* hp = hAll; const float* cp = cA;
  size_t hoff = 65536;
  int Mlvl = 65536;
  for (int lvl = 2; lvl <= 3; ++lvl) {
    Mlvl >>= 1;
    float* cn = (lvl & 1) ? cA : cB;
    gemm_fused<5,false><<<dim3(8,ceil8(DIV_UP(Mlvl,128))),256,0,stream>>>(
        (const char*)hp, nullptr, (const char*)ucatT, Mlvl, 512, 1024,
        b_Uiou, b_Uf, cp, hAll + hoff*256, cn);
    hp = hAll + hoff*256; cp = cn; hoff += Mlvl;
  }

  // ---- levels 4..11: one persistent launch, 7 device-scope grid barriers ----
  hipMemsetAsync(bar, 0, 4, stream);   // captured graph node -> re-zeroed every replay
  gemm_tail<<<dim3(8,64),256,0,stream>>>(
      (const char*)hAll, (const char*)ucatT, b_Uiou, b_Uf, cA, cB, hAll, bar);

  // ---- single deferred output projection over all internal nodes (131008 rows) ----
  outproj_v<<<2048,256,0,stream>>>(hAll, 131008, W_out, b_out, out + (size_t)131072*5);
}

// Round 16
// 475.318 us; speedup vs baseline: 4.1317x; 4.1317x over previous
//
#include <hip/hip_runtime.h>
#include <hip/hip_bf16.h>

typedef __attribute__((ext_vector_type(8))) short bfrag8;   // 8 bf16 in 4 VGPRs
typedef __attribute__((ext_vector_type(4))) float f32x4;

#define DIV_UP(a,b) (((a)+(b)-1)/(b))

__device__ __forceinline__ float sigm(float x){ return 1.0f/(1.0f + __expf(-x)); }
__device__ __forceinline__ float fast_tanh(float x){
  float ax = fabsf(x);
  float t = __expf(-2.0f*ax);
  float r = (1.0f - t)/(1.0f + t);
  return copysignf(r, x);
}
__device__ __forceinline__ float bf2f(short s){
  unsigned int u = ((unsigned int)(unsigned short)s) << 16;
  return __uint_as_float(u);
}
__device__ __forceinline__ unsigned short f2bf_bits(float x){
  __hip_bfloat16 b = __float2bfloat16(x);
  return *reinterpret_cast<unsigned short*>(&b);
}

#define GLOAD_LDS16(g, l) \
  __builtin_amdgcn_global_load_lds((const __attribute__((address_space(1))) void*)(g), \
                                   (__attribute__((address_space(3))) void*)(l), 16, 0, 0)

// ---------------- merged weight / embedding conversion (1 launch) ----------------
__global__ void conv_all(const float* __restrict__ emb, const float* __restrict__ Wf,
                         const float* __restrict__ Ui, const float* __restrict__ Uf,
                         __hip_bfloat16* __restrict__ oemb, __hip_bfloat16* __restrict__ owiou,
                         __hip_bfloat16* __restrict__ oucat){
  int idx = blockIdx.x*256 + threadIdx.x;
  if (idx < 32000*80) {
    int v = idx / 80, c = idx - v*80;
    ushort4 r;
    if (c < 75) {
      float4 f = *(const float4*)(emb + (size_t)v*300 + c*4);
      r.x = f2bf_bits(f.x); r.y = f2bf_bits(f.y); r.z = f2bf_bits(f.z); r.w = f2bf_bits(f.w);
    } else { r.x = r.y = r.z = r.w = 0; }
    *(ushort4*)((unsigned short*)oemb + (size_t)v*320 + c*4) = r;
    return;
  }
  idx -= 32000*80;
  if (idx < 768*320) {
    int n = idx / 320, k = idx - n*320;
    int eg = n / 48, rem = n - eg*48, gate = rem >> 4, es = rem & 15;
    int e = eg*16 + es;
    owiou[(size_t)n*320 + k] = __float2bfloat16(k < 300 ? Wf[(size_t)k*768 + gate*256 + e] : 0.0f);
    return;
  }
  idx -= 768*320;
  if (idx < 1280*512) {
    int n = idx >> 9, k = idx & 511;
    int eg = n / 80, rem = n - eg*80, gate = rem >> 4, es = rem & 15;
    int e = eg*16 + es;
    float v = (gate < 3) ? Ui[(size_t)k*768 + gate*256 + e]
                         : Uf[(size_t)k*512 + (gate-3)*256 + e];
    oucat[(size_t)n*512 + k] = __float2bfloat16(v);
  }
}

// ---------------- fused GEMM + gates, 2-phase double-buffered pipeline (round-8/10/12 best) ----
// Verified local optimum. Bracketing ledger (all A/B'd on this problem):
//  - (256,2): tie (r5)            - (256,4): 128-reg budget, 530 MB spill (r4)
//  - 4-deep 1-barrier: -18% (r9)  - reg-A per-lane: -30% (r11, 2x A VMEM requests)
//  - BM=256/8-wave (512,6): 85-reg budget -> 3 GB spill (r13); register file pins
//    148-reg waves at <=12 waves/CU -> larger tiles structurally impossible.
//  - persistent tail + device grid barriers: -1.2 ms (r15; AGENT-scope acq/rel L2
//    wb/inv per arrival+poll costs ~490K cyc/barrier -- launches are cheaper).
// Schedule: 2-buffer LDS (36.9 KB, 3 blk/CU), wave-exact counted vmcnt (L = own loads/stage),
// 2 barriers/step, XCD co-location swizzle (lx=by&7, ly=(by>>3)*8+bx; FETCH 277->117 MB).
// grid.y multiple of 8; tail blocks exit uniformly before any barrier.
template<int NG, bool G2>
__global__ __launch_bounds__(256, 3) void gemm_fused(
    const char* __restrict__ Ab,      // A bytes (direct) | h_voc bytes (G2: gather pairs)
    const int*  __restrict__ wid,     // G2 only: leaf wordids (children 2m, 2m+1)
    const char* __restrict__ Btb,     // interleaved [N][K] bf16
    int M, int K, int Kb,             // Kb = A row stride bytes (direct mode)
    const float* __restrict__ b_iou,  // [768] original layout
    const float* __restrict__ b_f,    // [512] (NG=5)
    const float* __restrict__ cprev,  // fp32 children c (table when G2)
    __hip_bfloat16* __restrict__ Hout, float* __restrict__ Cout)
{
  constexpr int GW  = NG*16;          // wave col width (one e-group, NG gates)
  constexpr int BN  = 2*GW;           // block cols
  constexpr int BCH = BN*4;           // B chunks (16B) per K-step
  constexpr int BUF = 8192 + BN*64;   // bytes per (A,B) buffer pair
  __shared__ __align__(16) char lds[2*BUF];

  const int lx = blockIdx.y & 7;
  const int ly = ((blockIdx.y >> 3) << 3) | (blockIdx.x & 7);
  const int row0 = ly*128;
  if (row0 >= M) return;              // padded grid.y tail (uniform per block)

  const int t = threadIdx.x, lane = t & 63, w = t >> 6;
  const int wr = w >> 1, wc = w & 1;
  const int frow = lane & 15, g = lane >> 4;
  const size_t colbase = (size_t)lx * BN;
  const size_t Kbyt = (size_t)K*2;

  // ---- ks-invariant staging descriptors (de-swizzled chunk -> (row,q)) ----
  const char* abase0[2]; const char* abase1[2];
  #pragma unroll
  for (int i = 0; i < 2; ++i) {
    int c = t + i*256;
    int rp = c >> 3, lc = (c & 7) ^ (rp & 7);
    int r = rp*2 + (lc >> 2), q = lc & 3;
    int row = row0 + r; row = row < M ? row : M-1;
    if constexpr (G2) {
      abase0[i] = Ab + (size_t)wid[2*row]  *512 + q*16;
      abase1[i] = Ab + (size_t)wid[2*row+1]*512 + q*16 - 512;
    } else {
      abase0[i] = Ab + (size_t)row*Kb + q*16;
      abase1[i] = abase0[i];
    }
  }
  const char* bbase[3];
  const int nb = (t < 128) ? ((NG==5) ? 3 : 2) : ((NG==5) ? 2 : 1);
  #pragma unroll
  for (int i = 0; i < 3; ++i) {
    int cb = t + i*256;
    if (cb < BCH) {
      int rp = cb >> 3, lc = (cb & 7) ^ (rp & 7);
      int r = rp*2 + (lc >> 2), q = lc & 3;
      bbase[i] = Btb + (colbase + r)*Kbyt + q*16;
    } else bbase[i] = Btb;
  }

  auto STAGE = [&](int b, int ks){
    const int kb0 = ks*64;
    char* la = lds + b*BUF;
    char* lb = la + 8192;
    #pragma unroll
    for (int i = 0; i < 2; ++i) {
      const char* s = (G2 && kb0 >= 512) ? abase1[i] + kb0 : abase0[i] + kb0;
      GLOAD_LDS16(s, la + (t + i*256)*16);
    }
    #pragma unroll
    for (int i = 0; i < 3; ++i)
      if (i < nb) GLOAD_LDS16(bbase[i] + kb0, lb + (t + i*256)*16);
  };

  // swizzled read offsets (lane-constant across mi/gi)
  const int fr2 = frow >> 1;
  const int pc  = (((frow & 1)*4 + g) ^ (fr2 & 7));
  const int aoff = wr*4096 + fr2*128 + pc*16;
  const int boff = wc*(GW*64) + fr2*128 + pc*16;

  f32x4 acc[4][NG] = {};
  const int nsteps = K >> 5;

  STAGE(0, 0);
  for (int ks = 0; ks < nsteps; ++ks) {
    const int b = ks & 1;
    if (ks + 1 < nsteps) {
      STAGE(b ^ 1, ks + 1);
      // wave-exact counted wait: outstanding <= own stage-load count L
      if constexpr (NG == 5) {
        if (w < 2) asm volatile("s_waitcnt vmcnt(5)" ::: "memory");
        else       asm volatile("s_waitcnt vmcnt(4)" ::: "memory");
      } else {
        if (w < 2) asm volatile("s_waitcnt vmcnt(4)" ::: "memory");
        else       asm volatile("s_waitcnt vmcnt(3)" ::: "memory");
      }
    } else {
      asm volatile("s_waitcnt vmcnt(0)" ::: "memory");
    }
    __builtin_amdgcn_s_barrier();          // buf[b] ready for all waves
    asm volatile("" ::: "memory");

    const char* la = lds + b*BUF;
    const char* lb = la + 8192;
    bfrag8 af[4], bfv[NG];
    #pragma unroll
    for (int mi = 0; mi < 4; ++mi) af[mi] = *(const bfrag8*)(la + aoff + mi*1024);
    #pragma unroll
    for (int gi = 0; gi < NG; ++gi) bfv[gi] = *(const bfrag8*)(lb + boff + gi*1024);
    #pragma unroll
    for (int mi = 0; mi < 4; ++mi)
      #pragma unroll
      for (int gi = 0; gi < NG; ++gi)
        acc[mi][gi] = __builtin_amdgcn_mfma_f32_16x16x32_bf16(af[mi], bfv[gi], acc[mi][gi], 0, 0, 0);

    asm volatile("" ::: "memory");
    __builtin_amdgcn_s_barrier();          // all waves done reading buf[b]
  }

  // ---- fused gate epilogue (C/D layout: col=frow, row=g*4+r) ----
  const int e = lx*32 + wc*16 + frow;
  const float bi = b_iou[e], bo = b_iou[256+e], bu = b_iou[512+e];
  float bf0 = 0.f, bf1 = 0.f;
  if constexpr (NG == 5) { bf0 = b_f[e]; bf1 = b_f[256+e]; }
  #pragma unroll
  for (int mi = 0; mi < 4; ++mi) {
    const int mb = row0 + wr*64 + mi*16 + g*4;
    #pragma unroll
    for (int r = 0; r < 4; ++r) {
      const int m = mb + r;
      if (m < M) {
        float cv = sigm(acc[mi][0][r] + bi) * fast_tanh(acc[mi][2][r] + bu);
        if constexpr (NG == 5) {
          const size_t c0i = G2 ? (size_t)wid[2*m]   : (size_t)(2*m);
          const size_t c1i = G2 ? (size_t)wid[2*m+1] : (size_t)(2*m+1);
          cv += sigm(acc[mi][3][r] + bf0) * cprev[c0i*256 + e]
              + sigm(acc[mi][4][r] + bf1) * cprev[c1i*256 + e];
        }
        Cout[(size_t)m*256 + e] = cv;
        Hout[(size_t)m*256 + e] = __float2bfloat16(sigm(acc[mi][1][r] + bo) * fast_tanh(cv));
      }
    }
  }
}

// ---------------- vectorized output projection ----------------
__global__ void outproj_v(const __hip_bfloat16* __restrict__ h, int M,
                          const float* __restrict__ Wout, const float* __restrict__ bout,
                          float* __restrict__ out){
  const int t = threadIdx.x;
  const int half = t >> 5, l32 = t & 31;
  const int e0 = l32 * 8;
  float wv[8][5];
  #pragma unroll
  for (int j = 0; j < 8; ++j)
    #pragma unroll
    for (int cl = 0; cl < 5; ++cl) wv[j][cl] = Wout[(e0+j)*5 + cl];
  const float b0 = bout[0], b1 = bout[1], b2 = bout[2], b3 = bout[3], b4 = bout[4];
  for (int row = blockIdx.x*8 + half; row < M; row += gridDim.x*8) {
    bfrag8 hv = *(const bfrag8*)((const short*)h + (size_t)row*256 + e0);
    float a0=0,a1=0,a2=0,a3=0,a4=0;
    #pragma unroll
    for (int j = 0; j < 8; ++j) {
      float x = bf2f(hv[j]);
      a0 += x*wv[j][0]; a1 += x*wv[j][1]; a2 += x*wv[j][2]; a3 += x*wv[j][3]; a4 += x*wv[j][4];
    }
    #pragma unroll
    for (int off = 16; off; off >>= 1) {
      a0 += __shfl_down(a0, off); a1 += __shfl_down(a1, off);
      a2 += __shfl_down(a2, off); a3 += __shfl_down(a3, off); a4 += __shfl_down(a4, off);
    }
    if (l32 == 0) {
      float* op = out + (size_t)row*5;
      op[0]=a0+b0; op[1]=a1+b1; op[2]=a2+b2; op[3]=a3+b3; op[4]=a4+b4;
    }
  }
}

// ---------------- leaf output scatter: out[p] = outvoc[wordid[p]] ----------------
__global__ void leaf_scatter(const int* __restrict__ wid, const float* __restrict__ outvoc,
                             float* __restrict__ out){
  int p = blockIdx.x*256 + threadIdx.x;
  if (p >= 131072) return;
  const float* s = outvoc + (size_t)wid[p]*5;
  float* d = out + (size_t)p*5;
  #pragma unroll
  for (int j = 0; j < 5; ++j) d[j] = s[j];
}

extern "C" void kernel_launch(void* const* d_in, const int* in_sizes, int n_in,
                              void* d_out, int out_size, void* d_ws, size_t ws_size,
                              hipStream_t stream) {
  const int* wordid   = (const int*)d_in[0];
  const float* emb    = (const float*)d_in[1];
  const float* W_iou  = (const float*)d_in[2];
  const float* b_Wiou = (const float*)d_in[3];
  const float* U_iou  = (const float*)d_in[4];
  const float* b_Uiou = (const float*)d_in[5];
  const float* U_f    = (const float*)d_in[6];
  const float* b_Uf   = (const float*)d_in[7];
  const float* W_out  = (const float*)d_in[8];
  const float* b_out  = (const float*)d_in[9];
  float* out = (float*)d_out;

  char* p = (char*)d_ws;
  auto take = [&](size_t bytes){ char* r = p; p += (bytes + 255) & ~(size_t)255; return r; };
  __hip_bfloat16* wiouT  = (__hip_bfloat16*)take((size_t)768*320*2);
  __hip_bfloat16* ucatT  = (__hip_bfloat16*)take((size_t)1280*512*2);
  __hip_bfloat16* h_voc  = (__hip_bfloat16*)take((size_t)32000*256*2);   // 16.4 MB
  float*          c_voc  = (float*)take((size_t)32000*256*4);            // 32.8 MB
  float*          outvoc = (float*)take((size_t)32000*5*4);
  __hip_bfloat16* hAll   = (__hip_bfloat16*)take((size_t)131008*256*2);  // 67.1 MB (lvls 1-11 packed)
  float*          cA     = (float*)take((size_t)65536*256*4);            // 67.1 MB
  float*          cB     = (float*)take((size_t)32768*256*4);            // 33.6 MB
  // embbf aliases cA: dead before first cA write (lvl-1 gates)
  __hip_bfloat16* embbf  = (__hip_bfloat16*)cA;                          // 20.5 MB

  auto ceil8 = [](int y){ return (y + 7) & ~7; };

  // ---- single merged conversion launch (emb + WiouT + UcatT) ----
  const int convN = 32000*80 + 768*320 + 1280*512;
  conv_all<<<DIV_UP(convN,256),256,0,stream>>>(emb, W_iou, U_iou, U_f, embbf, wiouT, ucatT);

  // ---- vocab precompute: h_voc/c_voc = leaf-gates(emb @ W_iou + b); outvoc = h_voc @ W_out + b ----
  gemm_fused<3,false><<<dim3(8,ceil8(250)),256,0,stream>>>(
      (const char*)embbf, nullptr, (const char*)wiouT, 32000, 320, 640,
      b_Wiou, nullptr, nullptr, h_voc, c_voc);
  outproj_v<<<1024,256,0,stream>>>(h_voc, 32000, W_out, b_out, outvoc);
  leaf_scatter<<<DIV_UP(131072,256),256,0,stream>>>(wordid, outvoc, out);

  // ---- level 1: gather children straight from vocab tables; h -> hAll[0:65536) ----
  gemm_fused<5,true><<<dim3(8,512),256,0,stream>>>(
      (const char*)h_voc, wordid, (const char*)ucatT, 65536, 512, 0,
      b_Uiou, b_Uf, c_voc, hAll, cA);

  // ---- levels 2..11: A reads prev level's packed h region; h appended into hAll ----
  const __hip_bfloat16* hp = hAll; const float* cp = cA;
  size_t hoff = 65536;
  int Mlvl = 65536;
  for (int lvl = 2; lvl <= 11; ++lvl) {
    Mlvl >>= 1;
    float* cn = (lvl & 1) ? cA : cB;    // lvl1 wrote cA; lvl2 reads cA writes cB; alternate
    gemm_fused<5,false><<<dim3(8,ceil8(DIV_UP(Mlvl,128))),256,0,stream>>>(
        (const char*)hp, nullptr, (const char*)ucatT, Mlvl, 512, 1024,
        b_Uiou, b_Uf, cp, hAll + hoff*256, cn);
    hp = hAll + hoff*256; cp = cn; hoff += Mlvl;
  }

  // ---- single deferred output projection over all internal nodes (131008 rows) ----
  outproj_v<<<2048,256,0,stream>>>(hAll, 131008, W_out, b_out, out + (size_t)131072*5);
}